// Round 2
// 129.089 us; speedup vs baseline: 1.0191x; 1.0191x over previous
//
#include <hip/hip_runtime.h>
#include <hip/hip_bf16.h>

typedef short s16x8 __attribute__((ext_vector_type(8)));
typedef float f32x4 __attribute__((ext_vector_type(4)));

#define LOG2E_2 2.8853900817779268f  // 2*log2(e)

__device__ __forceinline__ float fexp2(float x){ return __builtin_amdgcn_exp2f(x); }
__device__ __forceinline__ float frcp (float x){ return __builtin_amdgcn_rcpf(x); }
__device__ __forceinline__ float ftanh(float v){
    return 1.0f - 2.0f * frcp(1.0f + fexp2(LOG2E_2 * v));
}
__device__ __forceinline__ unsigned short f2bf(float v){
    __hip_bfloat16 h = __float2bfloat16(v);
    return __builtin_bit_cast(unsigned short, h);
}
__device__ __forceinline__ float bf2f(unsigned short u){
    return __bfloat162float(__builtin_bit_cast(__hip_bfloat16, u));
}
__device__ __forceinline__ f32x4 mfma32(s16x8 a, s16x8 b, f32x4 c){
    return __builtin_amdgcn_mfma_f32_16x16x32_bf16(a, b, c, 0, 0, 0);
}

// ---------- prep_all: merged prep_x + 2x prep_wt (saves 2 launches) ----------
// blocks 0..511    : x = [l0|l1] -> bf16 hi/lo split, [1024][512]
// blocks 512..1023 : transpose+split [Wfoh|Wfom] (512k x 1024n) -> w1t [1024n][512k]
// blocks 1024..1279: transpose W2 (1024k x 256n) -> w2t [256n][1024k]
__global__ __launch_bounds__(256) void prep_all(
    const float* __restrict__ l0, const float* __restrict__ l1,
    const float* __restrict__ Wfoh, const float* __restrict__ Wfom,
    const float* __restrict__ W2,
    unsigned short* __restrict__ xhi, unsigned short* __restrict__ xlo,
    unsigned short* __restrict__ w1hi, unsigned short* __restrict__ w1lo,
    unsigned short* __restrict__ w2hi, unsigned short* __restrict__ w2lo)
{
    __shared__ float F[32][33];
    const int t = threadIdx.x;
    const int bid = blockIdx.x;

    if (bid < 512) {
        int idx = (bid * 256 + t) * 4;
        int r = idx >> 9, c = idx & 511;
        float4 v = (c < 256) ? *(const float4*)(l0 + r*256 + c)
                             : *(const float4*)(l1 + r*256 + (c - 256));
        ushort4 h, l;
        h.x = f2bf(v.x); l.x = f2bf(v.x - bf2f(h.x));
        h.y = f2bf(v.y); l.y = f2bf(v.y - bf2f(h.y));
        h.z = f2bf(v.z); l.z = f2bf(v.z - bf2f(h.z));
        h.w = f2bf(v.w); l.w = f2bf(v.w - bf2f(h.w));
        *(ushort4*)(xhi + idx) = h;
        *(ushort4*)(xlo + idx) = l;
        return;
    }

    const float* srcA; const float* srcB;
    int splitN, lda, K, k0, n0;
    unsigned short *dhi, *dlo;
    if (bid < 1024) {
        int b = bid - 512;
        k0 = (b & 15) * 32; n0 = (b >> 4) * 32;
        srcA = Wfoh; srcB = Wfom; splitN = 512; lda = 512; K = 512;
        dhi = w1hi; dlo = w1lo;
    } else {
        int b = bid - 1024;
        k0 = (b & 31) * 32; n0 = (b >> 5) * 32;
        srcA = W2; srcB = W2; splitN = 1 << 30; lda = 256; K = 1024;
        dhi = w2hi; dlo = w2lo;
    }
    {
        int kk = t >> 3, n4 = (t & 7) * 4;
        int n = n0 + n4;
        const float* s = (n < splitN) ? (srcA + (k0+kk)*lda + n)
                                      : (srcB + (k0+kk)*lda + (n - splitN));
        float4 v = *(const float4*)s;
        F[kk][n4+0] = v.x; F[kk][n4+1] = v.y; F[kk][n4+2] = v.z; F[kk][n4+3] = v.w;
    }
    __syncthreads();
    {
        int nn = t >> 3, k4 = (t & 7) * 4;
        ushort4 h, l;
        float v0 = F[k4+0][nn]; h.x = f2bf(v0); l.x = f2bf(v0 - bf2f(h.x));
        float v1 = F[k4+1][nn]; h.y = f2bf(v1); l.y = f2bf(v1 - bf2f(h.y));
        float v2 = F[k4+2][nn]; h.z = f2bf(v2); l.z = f2bf(v2 - bf2f(h.z));
        float v3 = F[k4+3][nn]; h.w = f2bf(v3); l.w = f2bf(v3 - bf2f(h.w));
        *(ushort4*)(dhi + (n0+nn)*K + k0 + k4) = h;
        *(ushort4*)(dlo + (n0+nn)*K + k0 + k4) = l;
    }
}

// ---------- K1: hv = tanh(x @ [Wfoh|Wfom] + cb), split-bf16, 16x16x32 MFMA ----------
__global__ __launch_bounds__(256) void k1_mfma(
    const unsigned short* __restrict__ xhi, const unsigned short* __restrict__ xlo,
    const unsigned short* __restrict__ whi, const unsigned short* __restrict__ wlo,
    const float* __restrict__ cb,
    unsigned short* __restrict__ hvhi, unsigned short* __restrict__ hvlo)
{
    __shared__ unsigned short Ah[64][40], Al[64][40], Bh[32][40], Bl[32][40];
    const int t = threadIdx.x;
    const int r0 = blockIdx.y * 64, c0 = blockIdx.x * 32;
    const int w = t >> 6, lane = t & 63;
    const int m = lane & 15, quad = lane >> 4;

    const int arow = t >> 2, aseg = t & 3;
    const int brow = (t & 127) >> 2, bseg = t & 3;
    const bool doB = (t < 128);

    f32x4 acc0 = {0,0,0,0}, acc1 = {0,0,0,0};

    const unsigned short* pAh = xhi + (r0+arow)*512 + aseg*8;
    const unsigned short* pAl = xlo + (r0+arow)*512 + aseg*8;
    const unsigned short* pBh = whi + (c0+brow)*512 + bseg*8;
    const unsigned short* pBl = wlo + (c0+brow)*512 + bseg*8;

    uint4 pah = *(const uint4*)pAh;
    uint4 pal = *(const uint4*)pAl;
    uint4 pbh = {}, pbl = {};
    if (doB) { pbh = *(const uint4*)pBh; pbl = *(const uint4*)pBl; }

    for (int c = 0; c < 16; ++c) {
        __syncthreads();
        *(uint4*)&Ah[arow][aseg*8] = pah;
        *(uint4*)&Al[arow][aseg*8] = pal;
        if (doB) {
            *(uint4*)&Bh[brow][bseg*8] = pbh;
            *(uint4*)&Bl[brow][bseg*8] = pbl;
        }
        __syncthreads();
        if (c + 1 < 16) {
            int k0 = (c+1) * 32;
            pah = *(const uint4*)(pAh + k0);
            pal = *(const uint4*)(pAl + k0);
            if (doB) {
                pbh = *(const uint4*)(pBh + k0);
                pbl = *(const uint4*)(pBl + k0);
            }
        }
        {
            const int ko = quad*8;
            s16x8 ah  = *(const s16x8*)&Ah[w*16 + m][ko];
            s16x8 al  = *(const s16x8*)&Al[w*16 + m][ko];
            s16x8 b0h = *(const s16x8*)&Bh[m][ko];
            s16x8 b0l = *(const s16x8*)&Bl[m][ko];
            s16x8 b1h = *(const s16x8*)&Bh[16 + m][ko];
            s16x8 b1l = *(const s16x8*)&Bl[16 + m][ko];
            acc0 = mfma32(ah, b0h, acc0);
            acc0 = mfma32(ah, b0l, acc0);
            acc0 = mfma32(al, b0h, acc0);
            acc1 = mfma32(ah, b1h, acc1);
            acc1 = mfma32(ah, b1l, acc1);
            acc1 = mfma32(al, b1h, acc1);
        }
    }

    #pragma unroll
    for (int nt = 0; nt < 2; ++nt) {
        f32x4 a = nt ? acc1 : acc0;
        const int col = c0 + nt*16 + m;
        const float bias = cb[col];
        #pragma unroll
        for (int reg = 0; reg < 4; ++reg) {
            const int row = r0 + w*16 + quad*4 + reg;
            float v = ftanh(a[reg] + bias);
            unsigned short h = f2bf(v);
            unsigned short l = f2bf(v - bf2f(h));
            hvhi[row*1024 + col] = h;
            hvlo[row*1024 + col] = l;
        }
    }
}

// ---------- K2: P[1024][512] = exp2(LOG2E_2*(hv_half @ W2_half + bias)) ----------
__global__ __launch_bounds__(256) void k2_mfma(
    const unsigned short* __restrict__ hvhi, const unsigned short* __restrict__ hvlo,
    const unsigned short* __restrict__ w2hi, const unsigned short* __restrict__ w2lo,
    const float* __restrict__ h2b, float* __restrict__ P)
{
    __shared__ unsigned short Ah[64][40], Al[64][40], Bh[32][40], Bl[32][40];
    const int t = threadIdx.x;
    const int r0 = blockIdx.y * 64, c0 = blockIdx.x * 32;
    const int half = (c0 >= 256) ? 1 : 0;
    const int ho = half * 512;
    const int nw = c0 & 255;
    const int w = t >> 6, lane = t & 63;
    const int m = lane & 15, quad = lane >> 4;

    const int arow = t >> 2, aseg = t & 3;
    const int brow = (t & 127) >> 2, bseg = t & 3;
    const bool doB = (t < 128);

    f32x4 acc0 = {0,0,0,0}, acc1 = {0,0,0,0};

    const unsigned short* pAh = hvhi + (r0+arow)*1024 + ho + aseg*8;
    const unsigned short* pAl = hvlo + (r0+arow)*1024 + ho + aseg*8;
    const unsigned short* pBh = w2hi + (nw+brow)*1024 + ho + bseg*8;
    const unsigned short* pBl = w2lo + (nw+brow)*1024 + ho + bseg*8;

    uint4 pah = *(const uint4*)pAh;
    uint4 pal = *(const uint4*)pAl;
    uint4 pbh = {}, pbl = {};
    if (doB) { pbh = *(const uint4*)pBh; pbl = *(const uint4*)pBl; }

    for (int c = 0; c < 16; ++c) {
        __syncthreads();
        *(uint4*)&Ah[arow][aseg*8] = pah;
        *(uint4*)&Al[arow][aseg*8] = pal;
        if (doB) {
            *(uint4*)&Bh[brow][bseg*8] = pbh;
            *(uint4*)&Bl[brow][bseg*8] = pbl;
        }
        __syncthreads();
        if (c + 1 < 16) {
            int k0 = (c+1) * 32;
            pah = *(const uint4*)(pAh + k0);
            pal = *(const uint4*)(pAl + k0);
            if (doB) {
                pbh = *(const uint4*)(pBh + k0);
                pbl = *(const uint4*)(pBl + k0);
            }
        }
        {
            const int ko = quad*8;
            s16x8 ah  = *(const s16x8*)&Ah[w*16 + m][ko];
            s16x8 al  = *(const s16x8*)&Al[w*16 + m][ko];
            s16x8 b0h = *(const s16x8*)&Bh[m][ko];
            s16x8 b0l = *(const s16x8*)&Bl[m][ko];
            s16x8 b1h = *(const s16x8*)&Bh[16 + m][ko];
            s16x8 b1l = *(const s16x8*)&Bl[16 + m][ko];
            acc0 = mfma32(ah, b0h, acc0);
            acc0 = mfma32(ah, b0l, acc0);
            acc0 = mfma32(al, b0h, acc0);
            acc1 = mfma32(ah, b1h, acc1);
            acc1 = mfma32(ah, b1l, acc1);
            acc1 = mfma32(al, b1h, acc1);
        }
    }

    #pragma unroll
    for (int nt = 0; nt < 2; ++nt) {
        f32x4 a = nt ? acc1 : acc0;
        const int col = c0 + nt*16 + m;
        const float bias = half ? 0.0f : h2b[col];
        #pragma unroll
        for (int reg = 0; reg < 4; ++reg) {
            const int row = r0 + w*16 + quad*4 + reg;
            P[row*512 + col] = fexp2((a[reg] + bias) * LOG2E_2);
        }
    }
}

// ---------- K3 v3: score[i,j] = ob + sumw - 2*sum_h w[h]/(1 + ea[i,h]*eb[j,h]) ----------
// 4-way rcp combine: sum_{h=0..3} w_h/u_h = (p01*d23 + p23*d01) / (d01*d23)
//   u_h = 1 + ea*eb, d01 = u0*u1, p01 = w0*u1 + w1*u0   -> 14 VALU + 1 rcp per 4h
// Tile 64i x 32j, 256 thr, 4x2 outputs/thread (rows ty*4.., cols tx & tx+16),
// grid (32,16)=512 blocks. Rows padded to 68 floats (272B, 16B-aligned -> legal b128).
// Read conflicts: As rows stride-4 -> banks {0,16} (2-way, free);
// Bs rows stride-1 over tx -> banks tx*4 mod 32 (2-way, free).
__global__ __launch_bounds__(256) void k3_pairwise(
    const float* __restrict__ P, const float* __restrict__ w,
    const float* __restrict__ ob, float* __restrict__ out)
{
    __shared__ float As[64][68];   // ea chunk: [i][hh]
    __shared__ float Bs[32][68];   // eb chunk: [j][hh]
    __shared__ float wls[256];
    const int tid = threadIdx.x;
    const int tx = tid & 15;       // cols tx, tx+16
    const int ty = tid >> 4;       // rows ty*4..ty*4+3
    const int i0 = blockIdx.y * 64, j0 = blockIdx.x * 32;

    wls[tid] = w[tid];

    // staging: A chunk 64 rows x 64 h (4 float4/thread), B chunk 32 x 64 (2 float4/thread)
    const int ar = tid >> 2, ac = (tid & 3) * 16;
    const int br = tid >> 3, bc = (tid & 7) * 8;

    const float* pA = P + (i0 + ar) * 512 + ac;
    const float* pB = P + (j0 + br) * 512 + 256 + bc;

    float acc[4][2] = {};
    float4 ra[4], rb[2];
    #pragma unroll
    for (int k = 0; k < 4; ++k) ra[k] = *(const float4*)(pA + k*4);
    #pragma unroll
    for (int k = 0; k < 2; ++k) rb[k] = *(const float4*)(pB + k*4);

    for (int c = 0; c < 4; ++c) {
        __syncthreads();
        #pragma unroll
        for (int k = 0; k < 4; ++k) *(float4*)&As[ar][ac + k*4] = ra[k];
        #pragma unroll
        for (int k = 0; k < 2; ++k) *(float4*)&Bs[br][bc + k*4] = rb[k];
        __syncthreads();
        if (c + 1 < 4) {
            int off = (c + 1) * 64;
            #pragma unroll
            for (int k = 0; k < 4; ++k) ra[k] = *(const float4*)(pA + off + k*4);
            #pragma unroll
            for (int k = 0; k < 2; ++k) rb[k] = *(const float4*)(pB + off + k*4);
        }

        #pragma unroll 2
        for (int hh = 0; hh < 64; hh += 4) {
            float4 wv = *(const float4*)&wls[c*64 + hh];
            float4 av[4];
            #pragma unroll
            for (int r = 0; r < 4; ++r) av[r] = *(const float4*)&As[ty*4 + r][hh];
            float4 bv[2];
            #pragma unroll
            for (int q = 0; q < 2; ++q) bv[q] = *(const float4*)&Bs[tx + 16*q][hh];
            #pragma unroll
            for (int r = 0; r < 4; ++r)
                #pragma unroll
                for (int q = 0; q < 2; ++q) {
                    float u0 = fmaf(av[r].x, bv[q].x, 1.0f);
                    float u1 = fmaf(av[r].y, bv[q].y, 1.0f);
                    float u2 = fmaf(av[r].z, bv[q].z, 1.0f);
                    float u3 = fmaf(av[r].w, bv[q].w, 1.0f);
                    float d01 = u0 * u1;
                    float d23 = u2 * u3;
                    float p01 = fmaf(wv.x, u1, wv.y * u0);
                    float p23 = fmaf(wv.z, u3, wv.w * u2);
                    float num = fmaf(p01, d23, p23 * d01);
                    acc[r][q] = fmaf(num, frcp(d01 * d23), acc[r][q]);
                }
        }
    }

    float sumw = 0.0f;
    #pragma unroll
    for (int h = 0; h < 256; h += 4) {
        float4 wv = *(const float4*)&wls[h];
        sumw += (wv.x + wv.y) + (wv.z + wv.w);
    }
    const float base = ob[0] + sumw;
    #pragma unroll
    for (int r = 0; r < 4; ++r) {
        const int row = i0 + ty*4 + r;
        out[row*1024 + j0 + tx]      = base - 2.0f * acc[r][0];
        out[row*1024 + j0 + tx + 16] = base - 2.0f * acc[r][1];
    }
}

extern "C" void kernel_launch(void* const* d_in, const int* in_sizes, int n_in,
                              void* d_out, int out_size, void* d_ws, size_t ws_size,
                              hipStream_t stream) {
    const float* l0   = (const float*)d_in[0];  // lstms0 [1024,256]
    const float* l1   = (const float*)d_in[1];  // lstms1 [1024,256]
    const float* Wfoh = (const float*)d_in[2];  // [512,512]
    const float* Wfom = (const float*)d_in[3];  // [512,512]
    const float* cb   = (const float*)d_in[4];  // [1024]
    const float* W2   = (const float*)d_in[5];  // [1024,256]
    const float* h2b  = (const float*)d_in[6];  // [256]
    const float* w    = (const float*)d_in[7];  // [256]
    const float* ob   = (const float*)d_in[8];  // [1]
    float* out = (float*)d_out;                 // [1024,1024]

    // ws layout (11 MB total)
    unsigned short* hv_hi  = (unsigned short*)d_ws;          // [1024][1024] bf16
    unsigned short* hv_lo  = hv_hi + 1024*1024;
    float*          P      = (float*)(hv_lo + 1024*1024);    // [1024][512] fp32
    unsigned short* xs_hi  = (unsigned short*)(P + 1024*512);// [1024][512]
    unsigned short* xs_lo  = xs_hi + 1024*512;
    unsigned short* w1t_hi = xs_lo + 1024*512;               // [1024 n][512 k]
    unsigned short* w1t_lo = w1t_hi + 1024*512;
    unsigned short* w2t_hi = w1t_lo + 1024*512;              // [256 n][1024 k]
    unsigned short* w2t_lo = w2t_hi + 256*1024;

    prep_all<<<1280, 256, 0, stream>>>(l0, l1, Wfoh, Wfom, W2,
                                       xs_hi, xs_lo, w1t_hi, w1t_lo, w2t_hi, w2t_lo);
    k1_mfma<<<dim3(32,16), 256, 0, stream>>>(xs_hi, xs_lo, w1t_hi, w1t_lo, cb, hv_hi, hv_lo);
    k2_mfma<<<dim3(16,16), 256, 0, stream>>>(hv_hi, hv_lo, w2t_hi, w2t_lo, h2b, P);
    k3_pairwise<<<dim3(32,16), 256, 0, stream>>>(P, w, ob, out);
}

// Round 3
// 123.308 us; speedup vs baseline: 1.0669x; 1.0469x over previous
//
#include <hip/hip_runtime.h>
#include <hip/hip_bf16.h>

typedef short s16x8 __attribute__((ext_vector_type(8)));
typedef float f32x4 __attribute__((ext_vector_type(4)));

#define LOG2E_2 2.8853900817779268f  // 2*log2(e)

__device__ __forceinline__ float fexp2(float x){ return __builtin_amdgcn_exp2f(x); }
__device__ __forceinline__ float frcp (float x){ return __builtin_amdgcn_rcpf(x); }
__device__ __forceinline__ float ftanh(float v){
    return 1.0f - 2.0f * frcp(1.0f + fexp2(LOG2E_2 * v));
}
__device__ __forceinline__ unsigned short f2bf(float v){
    __hip_bfloat16 h = __float2bfloat16(v);
    return __builtin_bit_cast(unsigned short, h);
}
__device__ __forceinline__ float bf2f(unsigned short u){
    return __bfloat162float(__builtin_bit_cast(__hip_bfloat16, u));
}
__device__ __forceinline__ f32x4 mfma32(s16x8 a, s16x8 b, f32x4 c){
    return __builtin_amdgcn_mfma_f32_16x16x32_bf16(a, b, c, 0, 0, 0);
}

// ---------- prep_all: merged prep_x + 2x prep_wt ----------
// blocks 0..511    : x = [l0|l1] -> bf16 hi/lo split, [1024][512]
// blocks 512..1023 : transpose+split [Wfoh|Wfom] (512k x 1024n) -> w1t [1024n][512k]
// blocks 1024..1279: transpose W2 (1024k x 256n) -> w2t [256n][1024k]
__global__ __launch_bounds__(256) void prep_all(
    const float* __restrict__ l0, const float* __restrict__ l1,
    const float* __restrict__ Wfoh, const float* __restrict__ Wfom,
    const float* __restrict__ W2,
    unsigned short* __restrict__ xhi, unsigned short* __restrict__ xlo,
    unsigned short* __restrict__ w1hi, unsigned short* __restrict__ w1lo,
    unsigned short* __restrict__ w2hi, unsigned short* __restrict__ w2lo)
{
    __shared__ float F[32][33];
    const int t = threadIdx.x;
    const int bid = blockIdx.x;

    if (bid < 512) {
        int idx = (bid * 256 + t) * 4;
        int r = idx >> 9, c = idx & 511;
        float4 v = (c < 256) ? *(const float4*)(l0 + r*256 + c)
                             : *(const float4*)(l1 + r*256 + (c - 256));
        ushort4 h, l;
        h.x = f2bf(v.x); l.x = f2bf(v.x - bf2f(h.x));
        h.y = f2bf(v.y); l.y = f2bf(v.y - bf2f(h.y));
        h.z = f2bf(v.z); l.z = f2bf(v.z - bf2f(h.z));
        h.w = f2bf(v.w); l.w = f2bf(v.w - bf2f(h.w));
        *(ushort4*)(xhi + idx) = h;
        *(ushort4*)(xlo + idx) = l;
        return;
    }

    const float* srcA; const float* srcB;
    int splitN, lda, K, k0, n0;
    unsigned short *dhi, *dlo;
    if (bid < 1024) {
        int b = bid - 512;
        k0 = (b & 15) * 32; n0 = (b >> 4) * 32;
        srcA = Wfoh; srcB = Wfom; splitN = 512; lda = 512; K = 512;
        dhi = w1hi; dlo = w1lo;
    } else {
        int b = bid - 1024;
        k0 = (b & 31) * 32; n0 = (b >> 5) * 32;
        srcA = W2; srcB = W2; splitN = 1 << 30; lda = 256; K = 1024;
        dhi = w2hi; dlo = w2lo;
    }
    {
        int kk = t >> 3, n4 = (t & 7) * 4;
        int n = n0 + n4;
        const float* s = (n < splitN) ? (srcA + (k0+kk)*lda + n)
                                      : (srcB + (k0+kk)*lda + (n - splitN));
        float4 v = *(const float4*)s;
        F[kk][n4+0] = v.x; F[kk][n4+1] = v.y; F[kk][n4+2] = v.z; F[kk][n4+3] = v.w;
    }
    __syncthreads();
    {
        int nn = t >> 3, k4 = (t & 7) * 4;
        ushort4 h, l;
        float v0 = F[k4+0][nn]; h.x = f2bf(v0); l.x = f2bf(v0 - bf2f(h.x));
        float v1 = F[k4+1][nn]; h.y = f2bf(v1); l.y = f2bf(v1 - bf2f(h.y));
        float v2 = F[k4+2][nn]; h.z = f2bf(v2); l.z = f2bf(v2 - bf2f(h.z));
        float v3 = F[k4+3][nn]; h.w = f2bf(v3); l.w = f2bf(v3 - bf2f(h.w));
        *(ushort4*)(dhi + (n0+nn)*K + k0 + k4) = h;
        *(ushort4*)(dlo + (n0+nn)*K + k0 + k4) = l;
    }
}

// ---------- K1 v2: hv = tanh(x @ [Wfoh|Wfom] + cb) ----------
// Double-buffered LDS: 1 barrier per K-chunk (was 2). Prefetch lands across a
// full compute phase. Tile 64m x 32n, grid (32,16), 256 thr.
__global__ __launch_bounds__(256) void k1_mfma(
    const unsigned short* __restrict__ xhi, const unsigned short* __restrict__ xlo,
    const unsigned short* __restrict__ whi, const unsigned short* __restrict__ wlo,
    const float* __restrict__ cb,
    unsigned short* __restrict__ hvhi, unsigned short* __restrict__ hvlo)
{
    __shared__ unsigned short Ah[2][64][40], Al[2][64][40], Bh[2][32][40], Bl[2][32][40];
    const int t = threadIdx.x;
    const int r0 = blockIdx.y * 64, c0 = blockIdx.x * 32;
    const int w = t >> 6, lane = t & 63;
    const int m = lane & 15, quad = lane >> 4;

    const int arow = t >> 2, aseg = t & 3;
    const int brow = (t & 127) >> 2, bseg = t & 3;
    const bool doB = (t < 128);

    f32x4 acc0 = {0,0,0,0}, acc1 = {0,0,0,0};

    const unsigned short* pAh = xhi + (r0+arow)*512 + aseg*8;
    const unsigned short* pAl = xlo + (r0+arow)*512 + aseg*8;
    const unsigned short* pBh = whi + (c0+brow)*512 + bseg*8;
    const unsigned short* pBl = wlo + (c0+brow)*512 + bseg*8;

    uint4 pah = *(const uint4*)pAh;
    uint4 pal = *(const uint4*)pAl;
    uint4 pbh = {}, pbl = {};
    if (doB) { pbh = *(const uint4*)pBh; pbl = *(const uint4*)pBl; }

    // stage chunk0 -> buf0, then issue prefetch of chunk1
    *(uint4*)&Ah[0][arow][aseg*8] = pah;
    *(uint4*)&Al[0][arow][aseg*8] = pal;
    if (doB) {
        *(uint4*)&Bh[0][brow][bseg*8] = pbh;
        *(uint4*)&Bl[0][brow][bseg*8] = pbl;
    }
    pah = *(const uint4*)(pAh + 32);
    pal = *(const uint4*)(pAl + 32);
    if (doB) { pbh = *(const uint4*)(pBh + 32); pbl = *(const uint4*)(pBl + 32); }
    __syncthreads();

    #pragma unroll 2
    for (int c = 0; c < 16; ++c) {
        const int buf = c & 1;
        {
            const int ko = quad*8;
            s16x8 ah  = *(const s16x8*)&Ah[buf][w*16 + m][ko];
            s16x8 al  = *(const s16x8*)&Al[buf][w*16 + m][ko];
            s16x8 b0h = *(const s16x8*)&Bh[buf][m][ko];
            s16x8 b0l = *(const s16x8*)&Bl[buf][m][ko];
            s16x8 b1h = *(const s16x8*)&Bh[buf][16 + m][ko];
            s16x8 b1l = *(const s16x8*)&Bl[buf][16 + m][ko];
            acc0 = mfma32(ah, b0h, acc0);
            acc0 = mfma32(ah, b0l, acc0);
            acc0 = mfma32(al, b0h, acc0);
            acc1 = mfma32(ah, b1h, acc1);
            acc1 = mfma32(ah, b1l, acc1);
            acc1 = mfma32(al, b1h, acc1);
        }
        if (c + 1 < 16) {
            const int nb = buf ^ 1;
            *(uint4*)&Ah[nb][arow][aseg*8] = pah;
            *(uint4*)&Al[nb][arow][aseg*8] = pal;
            if (doB) {
                *(uint4*)&Bh[nb][brow][bseg*8] = pbh;
                *(uint4*)&Bl[nb][brow][bseg*8] = pbl;
            }
            if (c + 2 < 16) {
                const int k0 = (c+2) * 32;
                pah = *(const uint4*)(pAh + k0);
                pal = *(const uint4*)(pAl + k0);
                if (doB) { pbh = *(const uint4*)(pBh + k0); pbl = *(const uint4*)(pBl + k0); }
            }
            __syncthreads();
        }
    }

    #pragma unroll
    for (int nt = 0; nt < 2; ++nt) {
        f32x4 a = nt ? acc1 : acc0;
        const int col = c0 + nt*16 + m;
        const float bias = cb[col];
        #pragma unroll
        for (int reg = 0; reg < 4; ++reg) {
            const int row = r0 + w*16 + quad*4 + reg;
            float v = ftanh(a[reg] + bias);
            unsigned short h = f2bf(v);
            unsigned short l = f2bf(v - bf2f(h));
            hvhi[row*1024 + col] = h;
            hvlo[row*1024 + col] = l;
        }
    }
}

// ---------- K2 v2: P[1024][512] = exp2(LOG2E_2*(hv_half @ W2_half + bias)) ----------
// Double-buffered LDS, same structure as K1 v2.
__global__ __launch_bounds__(256) void k2_mfma(
    const unsigned short* __restrict__ hvhi, const unsigned short* __restrict__ hvlo,
    const unsigned short* __restrict__ w2hi, const unsigned short* __restrict__ w2lo,
    const float* __restrict__ h2b, float* __restrict__ P)
{
    __shared__ unsigned short Ah[2][64][40], Al[2][64][40], Bh[2][32][40], Bl[2][32][40];
    const int t = threadIdx.x;
    const int r0 = blockIdx.y * 64, c0 = blockIdx.x * 32;
    const int half = (c0 >= 256) ? 1 : 0;
    const int ho = half * 512;
    const int nw = c0 & 255;
    const int w = t >> 6, lane = t & 63;
    const int m = lane & 15, quad = lane >> 4;

    const int arow = t >> 2, aseg = t & 3;
    const int brow = (t & 127) >> 2, bseg = t & 3;
    const bool doB = (t < 128);

    f32x4 acc0 = {0,0,0,0}, acc1 = {0,0,0,0};

    const unsigned short* pAh = hvhi + (r0+arow)*1024 + ho + aseg*8;
    const unsigned short* pAl = hvlo + (r0+arow)*1024 + ho + aseg*8;
    const unsigned short* pBh = w2hi + (nw+brow)*1024 + ho + bseg*8;
    const unsigned short* pBl = w2lo + (nw+brow)*1024 + ho + bseg*8;

    uint4 pah = *(const uint4*)pAh;
    uint4 pal = *(const uint4*)pAl;
    uint4 pbh = {}, pbl = {};
    if (doB) { pbh = *(const uint4*)pBh; pbl = *(const uint4*)pBl; }

    *(uint4*)&Ah[0][arow][aseg*8] = pah;
    *(uint4*)&Al[0][arow][aseg*8] = pal;
    if (doB) {
        *(uint4*)&Bh[0][brow][bseg*8] = pbh;
        *(uint4*)&Bl[0][brow][bseg*8] = pbl;
    }
    pah = *(const uint4*)(pAh + 32);
    pal = *(const uint4*)(pAl + 32);
    if (doB) { pbh = *(const uint4*)(pBh + 32); pbl = *(const uint4*)(pBl + 32); }
    __syncthreads();

    #pragma unroll 2
    for (int c = 0; c < 16; ++c) {
        const int buf = c & 1;
        {
            const int ko = quad*8;
            s16x8 ah  = *(const s16x8*)&Ah[buf][w*16 + m][ko];
            s16x8 al  = *(const s16x8*)&Al[buf][w*16 + m][ko];
            s16x8 b0h = *(const s16x8*)&Bh[buf][m][ko];
            s16x8 b0l = *(const s16x8*)&Bl[buf][m][ko];
            s16x8 b1h = *(const s16x8*)&Bh[buf][16 + m][ko];
            s16x8 b1l = *(const s16x8*)&Bl[buf][16 + m][ko];
            acc0 = mfma32(ah, b0h, acc0);
            acc0 = mfma32(ah, b0l, acc0);
            acc0 = mfma32(al, b0h, acc0);
            acc1 = mfma32(ah, b1h, acc1);
            acc1 = mfma32(ah, b1l, acc1);
            acc1 = mfma32(al, b1h, acc1);
        }
        if (c + 1 < 16) {
            const int nb = buf ^ 1;
            *(uint4*)&Ah[nb][arow][aseg*8] = pah;
            *(uint4*)&Al[nb][arow][aseg*8] = pal;
            if (doB) {
                *(uint4*)&Bh[nb][brow][bseg*8] = pbh;
                *(uint4*)&Bl[nb][brow][bseg*8] = pbl;
            }
            if (c + 2 < 16) {
                const int k0 = (c+2) * 32;
                pah = *(const uint4*)(pAh + k0);
                pal = *(const uint4*)(pAl + k0);
                if (doB) { pbh = *(const uint4*)(pBh + k0); pbl = *(const uint4*)(pBl + k0); }
            }
            __syncthreads();
        }
    }

    #pragma unroll
    for (int nt = 0; nt < 2; ++nt) {
        f32x4 a = nt ? acc1 : acc0;
        const int col = c0 + nt*16 + m;
        const float bias = half ? 0.0f : h2b[col];
        #pragma unroll
        for (int reg = 0; reg < 4; ++reg) {
            const int row = r0 + w*16 + quad*4 + reg;
            P[row*512 + col] = fexp2((a[reg] + bias) * LOG2E_2);
        }
    }
}

// ---------- K3 v4: score[i,j] = ob + sumw - 2*sum_h w[h]/(1 + ea[i,h]*eb[j,h]) ----------
// Occupancy fix: tile 32i x 32j, grid (32,32)=1024 blocks -> 4 blocks/CU (LDS 35KB),
// 16 waves/CU. Double-buffered LDS: 1 barrier/chunk. 2x2 outputs/thread
// (rows ty,ty+16 ; cols tx,tx+16). 4-way rcp combine kept (14 VALU + 1 rcp per 4h).
__global__ __launch_bounds__(256) void k3_pairwise(
    const float* __restrict__ P, const float* __restrict__ w,
    const float* __restrict__ ob, float* __restrict__ out)
{
    __shared__ float As[2][32][68];   // ea chunk: [i][hh], 272B rows (16B aligned)
    __shared__ float Bs[2][32][68];   // eb chunk: [j][hh]
    __shared__ float wls[256];
    const int tid = threadIdx.x;
    const int tx = tid & 15;          // cols tx, tx+16
    const int ty = tid >> 4;          // rows ty, ty+16
    const int i0 = blockIdx.y * 32, j0 = blockIdx.x * 32;

    wls[tid] = w[tid];

    // staging: 32 rows x 64 h per chunk = 2048 floats; 8 floats (2 float4) per thread
    const int ar = tid >> 3, ac = (tid & 7) * 8;

    const float* pA = P + (i0 + ar) * 512 + ac;
    const float* pB = P + (j0 + ar) * 512 + 256 + ac;

    float4 ra0 = *(const float4*)(pA);
    float4 ra1 = *(const float4*)(pA + 4);
    float4 rb0 = *(const float4*)(pB);
    float4 rb1 = *(const float4*)(pB + 4);

    // stage chunk0 -> buf0, prefetch chunk1
    *(float4*)&As[0][ar][ac]   = ra0;
    *(float4*)&As[0][ar][ac+4] = ra1;
    *(float4*)&Bs[0][ar][ac]   = rb0;
    *(float4*)&Bs[0][ar][ac+4] = rb1;
    ra0 = *(const float4*)(pA + 64);
    ra1 = *(const float4*)(pA + 68);
    rb0 = *(const float4*)(pB + 64);
    rb1 = *(const float4*)(pB + 68);
    __syncthreads();

    float acc[2][2] = {};

    #pragma unroll 2
    for (int c = 0; c < 4; ++c) {
        const int buf = c & 1;
        #pragma unroll 4
        for (int hh = 0; hh < 64; hh += 4) {
            float4 wv = *(const float4*)&wls[c*64 + hh];
            float4 av[2], bv[2];
            av[0] = *(const float4*)&As[buf][ty][hh];
            av[1] = *(const float4*)&As[buf][ty+16][hh];
            bv[0] = *(const float4*)&Bs[buf][tx][hh];
            bv[1] = *(const float4*)&Bs[buf][tx+16][hh];
            #pragma unroll
            for (int r = 0; r < 2; ++r)
                #pragma unroll
                for (int q = 0; q < 2; ++q) {
                    float u0 = fmaf(av[r].x, bv[q].x, 1.0f);
                    float u1 = fmaf(av[r].y, bv[q].y, 1.0f);
                    float u2 = fmaf(av[r].z, bv[q].z, 1.0f);
                    float u3 = fmaf(av[r].w, bv[q].w, 1.0f);
                    float d01 = u0 * u1;
                    float d23 = u2 * u3;
                    float p01 = fmaf(wv.x, u1, wv.y * u0);
                    float p23 = fmaf(wv.z, u3, wv.w * u2);
                    float num = fmaf(p01, d23, p23 * d01);
                    acc[r][q] = fmaf(num, frcp(d01 * d23), acc[r][q]);
                }
        }
        if (c + 1 < 4) {
            const int nb = buf ^ 1;
            *(float4*)&As[nb][ar][ac]   = ra0;
            *(float4*)&As[nb][ar][ac+4] = ra1;
            *(float4*)&Bs[nb][ar][ac]   = rb0;
            *(float4*)&Bs[nb][ar][ac+4] = rb1;
            if (c + 2 < 4) {
                const int off = (c + 2) * 64;
                ra0 = *(const float4*)(pA + off);
                ra1 = *(const float4*)(pA + off + 4);
                rb0 = *(const float4*)(pB + off);
                rb1 = *(const float4*)(pB + off + 4);
            }
            __syncthreads();
        }
    }

    float sumw = 0.0f;
    #pragma unroll
    for (int h = 0; h < 256; h += 4) {
        float4 wv = *(const float4*)&wls[h];
        sumw += (wv.x + wv.y) + (wv.z + wv.w);
    }
    const float base = ob[0] + sumw;
    out[(i0+ty)*1024    + j0+tx]      = base - 2.0f * acc[0][0];
    out[(i0+ty)*1024    + j0+tx+16]   = base - 2.0f * acc[0][1];
    out[(i0+ty+16)*1024 + j0+tx]      = base - 2.0f * acc[1][0];
    out[(i0+ty+16)*1024 + j0+tx+16]   = base - 2.0f * acc[1][1];
}

extern "C" void kernel_launch(void* const* d_in, const int* in_sizes, int n_in,
                              void* d_out, int out_size, void* d_ws, size_t ws_size,
                              hipStream_t stream) {
    const float* l0   = (const float*)d_in[0];  // lstms0 [1024,256]
    const float* l1   = (const float*)d_in[1];  // lstms1 [1024,256]
    const float* Wfoh = (const float*)d_in[2];  // [512,512]
    const float* Wfom = (const float*)d_in[3];  // [512,512]
    const float* cb   = (const float*)d_in[4];  // [1024]
    const float* W2   = (const float*)d_in[5];  // [1024,256]
    const float* h2b  = (const float*)d_in[6];  // [256]
    const float* w    = (const float*)d_in[7];  // [256]
    const float* ob   = (const float*)d_in[8];  // [1]
    float* out = (float*)d_out;                 // [1024,1024]

    // ws layout (11 MB total)
    unsigned short* hv_hi  = (unsigned short*)d_ws;          // [1024][1024] bf16
    unsigned short* hv_lo  = hv_hi + 1024*1024;
    float*          P      = (float*)(hv_lo + 1024*1024);    // [1024][512] fp32
    unsigned short* xs_hi  = (unsigned short*)(P + 1024*512);// [1024][512]
    unsigned short* xs_lo  = xs_hi + 1024*512;
    unsigned short* w1t_hi = xs_lo + 1024*512;               // [1024 n][512 k]
    unsigned short* w1t_lo = w1t_hi + 1024*512;
    unsigned short* w2t_hi = w1t_lo + 1024*512;              // [256 n][1024 k]
    unsigned short* w2t_lo = w2t_hi + 256*1024;

    prep_all<<<1280, 256, 0, stream>>>(l0, l1, Wfoh, Wfom, W2,
                                       xs_hi, xs_lo, w1t_hi, w1t_lo, w2t_hi, w2t_lo);
    k1_mfma<<<dim3(32,16), 256, 0, stream>>>(xs_hi, xs_lo, w1t_hi, w1t_lo, cb, hv_hi, hv_lo);
    k2_mfma<<<dim3(16,16), 256, 0, stream>>>(hv_hi, hv_lo, w2t_hi, w2t_lo, h2b, P);
    k3_pairwise<<<dim3(32,32), 256, 0, stream>>>(P, w, ob, out);
}

// Round 4
// 119.105 us; speedup vs baseline: 1.1045x; 1.0353x over previous
//
#include <hip/hip_runtime.h>
#include <hip/hip_bf16.h>

typedef short s16x8 __attribute__((ext_vector_type(8)));
typedef float f32x4 __attribute__((ext_vector_type(4)));

#define LOG2E_2 2.8853900817779268f  // 2*log2(e)

__device__ __forceinline__ float fexp2(float x){ return __builtin_amdgcn_exp2f(x); }
__device__ __forceinline__ float frcp (float x){ return __builtin_amdgcn_rcpf(x); }
__device__ __forceinline__ float ftanh(float v){
    return 1.0f - 2.0f * frcp(1.0f + fexp2(LOG2E_2 * v));
}
__device__ __forceinline__ unsigned short f2bf(float v){
    __hip_bfloat16 h = __float2bfloat16(v);
    return __builtin_bit_cast(unsigned short, h);
}
__device__ __forceinline__ float bf2f(unsigned short u){
    return __bfloat162float(__builtin_bit_cast(__hip_bfloat16, u));
}
__device__ __forceinline__ f32x4 mfma32(s16x8 a, s16x8 b, f32x4 c){
    return __builtin_amdgcn_mfma_f32_16x16x32_bf16(a, b, c, 0, 0, 0);
}
// split fp32x4 -> bf16 hi + residual lo (identical rounding path to old prep)
__device__ __forceinline__ void cvt4(float4 v, ushort4& h, ushort4& l){
    h.x = f2bf(v.x); l.x = f2bf(v.x - bf2f(h.x));
    h.y = f2bf(v.y); l.y = f2bf(v.y - bf2f(h.y));
    h.z = f2bf(v.z); l.z = f2bf(v.z - bf2f(h.z));
    h.w = f2bf(v.w); l.w = f2bf(v.w - bf2f(h.w));
}

// ---------- K1': hv = tanh(x @ [Wfoh|Wfom] + cb) -- fp32 in, split done inline ----------
// Tile 64m x 32n, grid (32,16)=512 blocks, 256 thr. Double-buffered LDS, 1 barrier/chunk.
// A: x rows loaded fp32 (same bytes as hi+lo), converted in regs during staging.
// B: W column strip loaded fp32 (4 k-consecutive elems/thread, lane-coalesced over n),
//    converted + transposed into LDS (b64 writes). No prep kernel, no w1t/xs roundtrip.
__global__ __launch_bounds__(256) void k1_fused(
    const float* __restrict__ l0, const float* __restrict__ l1,
    const float* __restrict__ Wfoh, const float* __restrict__ Wfom,
    const float* __restrict__ cb,
    unsigned short* __restrict__ hvhi, unsigned short* __restrict__ hvlo)
{
    __shared__ unsigned short Ah[2][64][40], Al[2][64][40], Bh[2][32][40], Bl[2][32][40];
    const int t = threadIdx.x;
    const int r0 = blockIdx.y * 64, c0 = blockIdx.x * 32;
    const int w = t >> 6, lane = t & 63;
    const int m = lane & 15, quad = lane >> 4;

    const int arow = t >> 2, aseg = t & 3;   // A: 8 floats @ cols aseg*8, row arow
    const int nn = t & 31, kq = t >> 5;      // B: col nn, k rows kq*4..kq*4+3

    const float* xrow0 = l0 + (r0+arow)*256 + aseg*8;
    const float* xrow1 = l1 + (r0+arow)*256 + aseg*8;
    const float* wcol  = (c0 < 512) ? (Wfoh + c0 + nn) : (Wfom + (c0 - 512) + nn);

    f32x4 acc0 = {0,0,0,0}, acc1 = {0,0,0,0};

    float4 fa0, fa1, fb;
    // ---- load chunk k0 into prefetch regs ----
    #define K1_LOAD(k0_) do { \
        const float* pa_ = ((k0_) < 256) ? (xrow0 + (k0_)) : (xrow1 + ((k0_) - 256)); \
        fa0 = *(const float4*)pa_; \
        fa1 = *(const float4*)(pa_ + 4); \
        const float* pb_ = wcol + ((k0_) + kq*4) * 512; \
        fb.x = pb_[0]; fb.y = pb_[512]; fb.z = pb_[1024]; fb.w = pb_[1536]; \
    } while(0)
    // ---- convert + write prefetch regs into LDS buf ----
    #define K1_STAGE(buf_) do { \
        ushort4 h0_, lo0_, h1_, lo1_, bh_, bl_; \
        cvt4(fa0, h0_, lo0_); cvt4(fa1, h1_, lo1_); cvt4(fb, bh_, bl_); \
        *(ushort4*)&Ah[buf_][arow][aseg*8]     = h0_; \
        *(ushort4*)&Ah[buf_][arow][aseg*8 + 4] = h1_; \
        *(ushort4*)&Al[buf_][arow][aseg*8]     = lo0_; \
        *(ushort4*)&Al[buf_][arow][aseg*8 + 4] = lo1_; \
        *(ushort4*)&Bh[buf_][nn][kq*4] = bh_; \
        *(ushort4*)&Bl[buf_][nn][kq*4] = bl_; \
    } while(0)

    K1_LOAD(0);
    K1_STAGE(0);
    K1_LOAD(32);
    __syncthreads();

    for (int c = 0; c < 16; ++c) {
        const int buf = c & 1;
        {
            const int ko = quad*8;
            s16x8 ah  = *(const s16x8*)&Ah[buf][w*16 + m][ko];
            s16x8 al  = *(const s16x8*)&Al[buf][w*16 + m][ko];
            s16x8 b0h = *(const s16x8*)&Bh[buf][m][ko];
            s16x8 b0l = *(const s16x8*)&Bl[buf][m][ko];
            s16x8 b1h = *(const s16x8*)&Bh[buf][16 + m][ko];
            s16x8 b1l = *(const s16x8*)&Bl[buf][16 + m][ko];
            acc0 = mfma32(ah, b0h, acc0);
            acc0 = mfma32(ah, b0l, acc0);
            acc0 = mfma32(al, b0h, acc0);
            acc1 = mfma32(ah, b1h, acc1);
            acc1 = mfma32(ah, b1l, acc1);
            acc1 = mfma32(al, b1h, acc1);
        }
        if (c + 1 < 16) {
            K1_STAGE(buf ^ 1);
            if (c + 2 < 16) K1_LOAD((c + 2) * 32);
            __syncthreads();
        }
    }
    #undef K1_LOAD
    #undef K1_STAGE

    #pragma unroll
    for (int nt = 0; nt < 2; ++nt) {
        f32x4 a = nt ? acc1 : acc0;
        const int col = c0 + nt*16 + m;
        const float bias = cb[col];
        #pragma unroll
        for (int reg = 0; reg < 4; ++reg) {
            const int row = r0 + w*16 + quad*4 + reg;
            float v = ftanh(a[reg] + bias);
            unsigned short h = f2bf(v);
            unsigned short l = f2bf(v - bf2f(h));
            hvhi[row*1024 + col] = h;
            hvlo[row*1024 + col] = l;
        }
    }
}

// ---------- K2': P[1024][512] = exp2(LOG2E_2*(hv_half @ W2_half + bias)) ----------
// Tile 32m x 32n, grid (16,32)=512 blocks (2/CU, was 1/CU). W2 loaded fp32 and
// converted/transposed inline (no w2t). Double-buffered LDS, 1 barrier/chunk.
// Wave w -> 16x16 output tile (wm=w&1 rows, wn=w>>1 cols), 3 MFMA/chunk.
__global__ __launch_bounds__(256) void k2_fused(
    const unsigned short* __restrict__ hvhi, const unsigned short* __restrict__ hvlo,
    const float* __restrict__ W2, const float* __restrict__ h2b,
    float* __restrict__ P)
{
    __shared__ unsigned short Ah[2][32][40], Al[2][32][40], Bh[2][32][40], Bl[2][32][40];
    const int t = threadIdx.x;
    const int r0 = blockIdx.y * 32, c0 = blockIdx.x * 32;
    const int half = (c0 >= 256) ? 1 : 0;
    const int ho = half * 512;
    const int nw = c0 & 255;
    const int w = t >> 6, lane = t & 63;
    const int m = lane & 15, quad = lane >> 4;
    const int wm = w & 1, wn = w >> 1;

    const int arow = t >> 3, aseg = t & 7;   // A: ushort4 @ cols aseg*4, row arow
    const int nn = t & 31, kq = t >> 5;      // B: col nn, k rows kq*4..kq*4+3

    const unsigned short* pAh = hvhi + (r0+arow)*1024 + ho + aseg*4;
    const unsigned short* pAl = hvlo + (r0+arow)*1024 + ho + aseg*4;
    const float* wcol = W2 + ho*256 + nw + nn;   // element k: wcol[k*256]

    f32x4 acc = {0,0,0,0};

    uint2 pa_h, pa_l;
    float4 fb;
    #define K2_LOAD(k0_) do { \
        pa_h = *(const uint2*)(pAh + (k0_)); \
        pa_l = *(const uint2*)(pAl + (k0_)); \
        const float* pb_ = wcol + ((k0_) + kq*4) * 256; \
        fb.x = pb_[0]; fb.y = pb_[256]; fb.z = pb_[512]; fb.w = pb_[768]; \
    } while(0)
    #define K2_STAGE(buf_) do { \
        ushort4 bh_, bl_; \
        cvt4(fb, bh_, bl_); \
        *(uint2*)&Ah[buf_][arow][aseg*4] = pa_h; \
        *(uint2*)&Al[buf_][arow][aseg*4] = pa_l; \
        *(ushort4*)&Bh[buf_][nn][kq*4] = bh_; \
        *(ushort4*)&Bl[buf_][nn][kq*4] = bl_; \
    } while(0)

    K2_LOAD(0);
    K2_STAGE(0);
    K2_LOAD(32);
    __syncthreads();

    for (int c = 0; c < 16; ++c) {
        const int buf = c & 1;
        {
            const int ko = quad*8;
            s16x8 ah = *(const s16x8*)&Ah[buf][wm*16 + m][ko];
            s16x8 al = *(const s16x8*)&Al[buf][wm*16 + m][ko];
            s16x8 bh = *(const s16x8*)&Bh[buf][wn*16 + m][ko];
            s16x8 bl = *(const s16x8*)&Bl[buf][wn*16 + m][ko];
            acc = mfma32(ah, bh, acc);
            acc = mfma32(ah, bl, acc);
            acc = mfma32(al, bh, acc);
        }
        if (c + 1 < 16) {
            K2_STAGE(buf ^ 1);
            if (c + 2 < 16) K2_LOAD((c + 2) * 32);
            __syncthreads();
        }
    }
    #undef K2_LOAD
    #undef K2_STAGE

    {
        const int col = c0 + wn*16 + m;
        const float bias = half ? 0.0f : h2b[col];
        #pragma unroll
        for (int reg = 0; reg < 4; ++reg) {
            const int row = r0 + wm*16 + quad*4 + reg;
            P[row*512 + col] = fexp2((acc[reg] + bias) * LOG2E_2);
        }
    }
}

// ---------- K3 v4: score[i,j] = ob + sumw - 2*sum_h w[h]/(1 + ea[i,h]*eb[j,h]) ----------
// (unchanged from round 3) 32x32 tile, grid (32,32)=1024 blocks (4/CU), double-buffered,
// 2x2 outputs/thread, 4-way rcp combine (14 VALU + 1 rcp per 4h).
__global__ __launch_bounds__(256) void k3_pairwise(
    const float* __restrict__ P, const float* __restrict__ w,
    const float* __restrict__ ob, float* __restrict__ out)
{
    __shared__ float As[2][32][68];
    __shared__ float Bs[2][32][68];
    __shared__ float wls[256];
    const int tid = threadIdx.x;
    const int tx = tid & 15;          // cols tx, tx+16
    const int ty = tid >> 4;          // rows ty, ty+16
    const int i0 = blockIdx.y * 32, j0 = blockIdx.x * 32;

    wls[tid] = w[tid];

    const int ar = tid >> 3, ac = (tid & 7) * 8;

    const float* pA = P + (i0 + ar) * 512 + ac;
    const float* pB = P + (j0 + ar) * 512 + 256 + ac;

    float4 ra0 = *(const float4*)(pA);
    float4 ra1 = *(const float4*)(pA + 4);
    float4 rb0 = *(const float4*)(pB);
    float4 rb1 = *(const float4*)(pB + 4);

    *(float4*)&As[0][ar][ac]   = ra0;
    *(float4*)&As[0][ar][ac+4] = ra1;
    *(float4*)&Bs[0][ar][ac]   = rb0;
    *(float4*)&Bs[0][ar][ac+4] = rb1;
    ra0 = *(const float4*)(pA + 64);
    ra1 = *(const float4*)(pA + 68);
    rb0 = *(const float4*)(pB + 64);
    rb1 = *(const float4*)(pB + 68);
    __syncthreads();

    float acc[2][2] = {};

    #pragma unroll 2
    for (int c = 0; c < 4; ++c) {
        const int buf = c & 1;
        #pragma unroll 4
        for (int hh = 0; hh < 64; hh += 4) {
            float4 wv = *(const float4*)&wls[c*64 + hh];
            float4 av[2], bv[2];
            av[0] = *(const float4*)&As[buf][ty][hh];
            av[1] = *(const float4*)&As[buf][ty+16][hh];
            bv[0] = *(const float4*)&Bs[buf][tx][hh];
            bv[1] = *(const float4*)&Bs[buf][tx+16][hh];
            #pragma unroll
            for (int r = 0; r < 2; ++r)
                #pragma unroll
                for (int q = 0; q < 2; ++q) {
                    float u0 = fmaf(av[r].x, bv[q].x, 1.0f);
                    float u1 = fmaf(av[r].y, bv[q].y, 1.0f);
                    float u2 = fmaf(av[r].z, bv[q].z, 1.0f);
                    float u3 = fmaf(av[r].w, bv[q].w, 1.0f);
                    float d01 = u0 * u1;
                    float d23 = u2 * u3;
                    float p01 = fmaf(wv.x, u1, wv.y * u0);
                    float p23 = fmaf(wv.z, u3, wv.w * u2);
                    float num = fmaf(p01, d23, p23 * d01);
                    acc[r][q] = fmaf(num, frcp(d01 * d23), acc[r][q]);
                }
        }
        if (c + 1 < 4) {
            const int nb = buf ^ 1;
            *(float4*)&As[nb][ar][ac]   = ra0;
            *(float4*)&As[nb][ar][ac+4] = ra1;
            *(float4*)&Bs[nb][ar][ac]   = rb0;
            *(float4*)&Bs[nb][ar][ac+4] = rb1;
            if (c + 2 < 4) {
                const int off = (c + 2) * 64;
                ra0 = *(const float4*)(pA + off);
                ra1 = *(const float4*)(pA + off + 4);
                rb0 = *(const float4*)(pB + off);
                rb1 = *(const float4*)(pB + off + 4);
            }
            __syncthreads();
        }
    }

    float sumw = 0.0f;
    #pragma unroll
    for (int h = 0; h < 256; h += 4) {
        float4 wv = *(const float4*)&wls[h];
        sumw += (wv.x + wv.y) + (wv.z + wv.w);
    }
    const float base = ob[0] + sumw;
    out[(i0+ty)*1024    + j0+tx]      = base - 2.0f * acc[0][0];
    out[(i0+ty)*1024    + j0+tx+16]   = base - 2.0f * acc[0][1];
    out[(i0+ty+16)*1024 + j0+tx]      = base - 2.0f * acc[1][0];
    out[(i0+ty+16)*1024 + j0+tx+16]   = base - 2.0f * acc[1][1];
}

extern "C" void kernel_launch(void* const* d_in, const int* in_sizes, int n_in,
                              void* d_out, int out_size, void* d_ws, size_t ws_size,
                              hipStream_t stream) {
    const float* l0   = (const float*)d_in[0];  // lstms0 [1024,256]
    const float* l1   = (const float*)d_in[1];  // lstms1 [1024,256]
    const float* Wfoh = (const float*)d_in[2];  // [512,512]
    const float* Wfom = (const float*)d_in[3];  // [512,512]
    const float* cb   = (const float*)d_in[4];  // [1024]
    const float* W2   = (const float*)d_in[5];  // [1024,256]
    const float* h2b  = (const float*)d_in[6];  // [256]
    const float* w    = (const float*)d_in[7];  // [256]
    const float* ob   = (const float*)d_in[8];  // [1]
    float* out = (float*)d_out;                 // [1024,1024]

    // ws layout: hv hi/lo (4MB) + P (2MB)
    unsigned short* hv_hi = (unsigned short*)d_ws;           // [1024][1024] bf16
    unsigned short* hv_lo = hv_hi + 1024*1024;
    float*          P     = (float*)(hv_lo + 1024*1024);     // [1024][512] fp32

    k1_fused<<<dim3(32,16), 256, 0, stream>>>(l0, l1, Wfoh, Wfom, cb, hv_hi, hv_lo);
    k2_fused<<<dim3(16,32), 256, 0, stream>>>(hv_hi, hv_lo, W2, h2b, P);
    k3_pairwise<<<dim3(32,32), 256, 0, stream>>>(P, w, ob, out);
}